// Round 6
// baseline (217.268 us; speedup 1.0000x reference)
//
#include <hip/hip_runtime.h>
#include <hip/hip_bf16.h>
#include <stdint.h>

#define IN_F   4096
#define OUT_F  4096
#define M_ROWS 2048
#define NG     32
#define GRP    128

typedef __bf16 bf16x8 __attribute__((ext_vector_type(8)));
typedef float  f32x4  __attribute__((ext_vector_type(4)));

typedef const void __attribute__((address_space(1))) cv_g;
typedef void       __attribute__((address_space(3))) v_l;

__device__ __forceinline__ void async16(const void* g, void* l) {
  // global -> LDS DMA, 16B/lane; LDS dest = wave-uniform base + lane*16.
  __builtin_amdgcn_global_load_lds((cv_g*)g, (v_l*)l, 16, 0, 0);
}

// perm dtype flag (fallback path only): 1 if int64, 0 if int32.
__device__ int g_perm_is64;

__global__ void decode_flag(const void* __restrict__ perm_raw) {
  if (threadIdx.x == 0 && blockIdx.x == 0) {
    const int* w = (const int*)perm_raw;
    int ok = 1;
    for (int j = 0; j < 32; ++j) {
      int lo = w[2 * j], hi = w[2 * j + 1];
      if (hi != 0 || lo < 0 || lo >= IN_F) { ok = 0; break; }
    }
    g_perm_is64 = ok;
  }
}

// Fused preprocessing (unchanged from R3 -- verified):
//   blocks [0, 2048):     xp[m, j] = bf16( x[m, perm[j]] )  (LDS-staged row gather)
//   blocks [2048, 10240): wf[o, k] = bf16( w_q[o,k] * s_w[k/128, o] )
__global__ __launch_bounds__(256) void prep(const float* __restrict__ x,
                                            const int* __restrict__ w_q,
                                            const float* __restrict__ s_w,
                                            const void* __restrict__ perm_raw,
                                            __hip_bfloat16* __restrict__ xp,
                                            __hip_bfloat16* __restrict__ wf) {
  __shared__ float sx[IN_F];
  __shared__ int sflag;
  const int b = blockIdx.x;
  const int t = threadIdx.x;

  if (b < M_ROWS) {
    const int m = b;
    const float* xr = x + (size_t)m * IN_F;
#pragma unroll
    for (int u = 0; u < 4; ++u) {
      int idx = (u * 256 + t) * 4;
      *(float4*)&sx[idx] = *(const float4*)&xr[idx];
    }
    if (t < 64) {
      const int* w = (const int*)perm_raw;
      int j = t & 31;  // lanes 32..63 duplicate 0..31 -> same ballot bits
      int lo = w[2 * j], hi = w[2 * j + 1];
      // int64 LE values in [0,4096): hi word always 0. int32 perm: w[2j+1] is a
      // perm value, ==0 for at most one j -> ballot never all-ones.
      int cond = (hi == 0 && lo >= 0 && lo < IN_F);
      unsigned long long bal = __ballot(cond);
      if (t == 0) sflag = (bal == ~0ull) ? 1 : 0;
    }
    __syncthreads();
    const int f = sflag;
    const long long* p64 = (const long long*)perm_raw;
    const int*       p32 = (const int*)perm_raw;
    const int jb = t * 16;
    __hip_bfloat16 tmp[16] __attribute__((aligned(16)));
#pragma unroll
    for (int u = 0; u < 16; ++u) {
      int pj = f ? (int)p64[jb + u] : p32[jb + u];
      tmp[u] = __float2bfloat16(sx[pj]);
    }
    *(uint4*)(xp + (size_t)m * IN_F + jb)     = *(const uint4*)&tmp[0];
    *(uint4*)(xp + (size_t)m * IN_F + jb + 8) = *(const uint4*)&tmp[8];
  } else {
    int tt = (b - M_ROWS) * 256 + t;
    int o  = tt >> 9;
    int kb = (tt & 511) << 3;
    float s = s_w[(size_t)(kb >> 7) * OUT_F + o];
    const int* wr = w_q + (size_t)o * IN_F + kb;
    int4 w0 = *(const int4*)wr;
    int4 w1 = *(const int4*)(wr + 4);
    __hip_bfloat16 tmp[8] __attribute__((aligned(16)));
    tmp[0] = __float2bfloat16((float)w0.x * s);
    tmp[1] = __float2bfloat16((float)w0.y * s);
    tmp[2] = __float2bfloat16((float)w0.z * s);
    tmp[3] = __float2bfloat16((float)w0.w * s);
    tmp[4] = __float2bfloat16((float)w1.x * s);
    tmp[5] = __float2bfloat16((float)w1.y * s);
    tmp[6] = __float2bfloat16((float)w1.z * s);
    tmp[7] = __float2bfloat16((float)w1.w * s);
    *(uint4*)(wf + (size_t)o * IN_F + kb) = *(const uint4*)tmp;
  }
}

// C[m,o] = sum_k A[m,k]*B[o,k] + bias[o]; A: M x K bf16, B: N x K bf16.
// R6: identical compute/staging to R5 (128x128 tile, BK=64 dbuf, swizzled LDS,
// 0 bank conflicts). ONE change: XCD-exclusive block remap. With the heuristic
// round-robin XCD = blockIdx % 8 and all 512 blocks co-resident (2/CU), XCD k
// exclusively owns B-column-tiles 4k..4k+3: each B k-window is pulled from L3
// once (by one XCD) and re-served from that XCD's L2 to its 16 row-blocks.
// A k-windows replicate across 8 XCDs (256 KB each -- fits 4 MB L2).
// Predicted: L3->L2 staging traffic 1.07 GB -> ~160 MB; L2 feeds at 34.5 TB/s.
__global__ __launch_bounds__(256) void gemm_bt(
    const __hip_bfloat16* __restrict__ A,
    const __hip_bfloat16* __restrict__ B,
    const float* __restrict__ bias,
    float* __restrict__ C) {
  __shared__ __hip_bfloat16 smem[2][16384];  // [parity][A 8192 | B 8192] = 64 KB

  const int tid  = threadIdx.x;
  const int wave = tid >> 6;
  const int lane = tid & 63;

  // XCD-exclusive remap (bijective on [0,512)):
  //   xcd = id & 7 owns B-cols bx in {4*xcd .. 4*xcd+3}, all 16 row-tiles.
  const int id   = blockIdx.x;
  const int bx   = ((id & 7) << 2) + ((id >> 3) & 3);
  const int by   = id >> 5;
  const int bm = by << 7;
  const int bn = bx << 7;

  const int wm = (wave >> 1) << 6;
  const int wn = (wave & 1) << 6;
  const int lrow = lane & 15;
  const int quad = lane >> 4;

  f32x4 acc[4][4] = {};

  // Staging: rounds h=0..3; linear chunk L = h*256 + wave*64 + lane in [0,1024);
  // row = L>>3, kc' = L&7, global kc = kc' ^ (row&7). LDS dest = uniform base
  // (h*256+wave*64)*8 elems + lane*16B (HW scatter).
  const __hip_bfloat16* gA[4];
  const __hip_bfloat16* gB[4];
  int lbase[4];
#pragma unroll
  for (int h = 0; h < 4; ++h) {
    int L   = h * 256 + wave * 64 + lane;
    int row = L >> 3;
    int kc  = (L & 7) ^ (row & 7);
    gA[h] = A + (size_t)(bm + row) * IN_F + kc * 8;
    gB[h] = B + (size_t)(bn + row) * IN_F + kc * 8;
    lbase[h] = (h * 256 + wave * 64) * 8;  // wave-uniform element offset
  }

  auto stage = [&](__hip_bfloat16* buf, int kn) {
#pragma unroll
    for (int h = 0; h < 4; ++h) {
      async16(gA[h] + kn, buf + lbase[h]);
      async16(gB[h] + kn, buf + 8192 + lbase[h]);
    }
  };

  auto compute = [&](const __hip_bfloat16* buf) {
#pragma unroll
    for (int s = 0; s < 2; ++s) {
      const int kcp = ((s << 2) + quad) ^ (lrow & 7);  // swizzled k-chunk pos
      bf16x8 af[4], bfr[4];
#pragma unroll
      for (int i = 0; i < 4; ++i)
        af[i] = *(const bf16x8*)&buf[(wm + i * 16 + lrow) * 64 + kcp * 8];
#pragma unroll
      for (int j = 0; j < 4; ++j)
        bfr[j] = *(const bf16x8*)&buf[8192 + (wn + j * 16 + lrow) * 64 + kcp * 8];
#pragma unroll
      for (int i = 0; i < 4; ++i)
#pragma unroll
        for (int j = 0; j < 4; ++j)
          acc[i][j] = __builtin_amdgcn_mfma_f32_16x16x32_bf16(af[i], bfr[j], acc[i][j], 0, 0, 0);
    }
  };

  stage(smem[0], 0);  // prologue
  for (int k0 = 0; k0 < IN_F; k0 += 128) {
    __syncthreads();               // smem[0]@k0 visible; prev reads of smem[1] done
    stage(smem[1], k0 + 64);       // k0+64 <= 4032 always valid
    compute(smem[0]);
    __syncthreads();               // smem[1]@k0+64 visible; reads of smem[0] done
    if (k0 + 128 < IN_F) stage(smem[0], k0 + 128);
    compute(smem[1]);
  }

  // Epilogue: C/D layout col=lane&15, row=quad*4+reg  [measured m89/m91]
#pragma unroll
  for (int i = 0; i < 4; ++i) {
    int row = bm + wm + i * 16 + quad * 4;
#pragma unroll
    for (int j = 0; j < 4; ++j) {
      int col = bn + wn + j * 16 + lrow;
      float bv = bias[col];
#pragma unroll
      for (int r = 0; r < 4; ++r)
        C[(size_t)(row + r) * OUT_F + col] = acc[i][j][r] + bv;
    }
  }
}

// Correct-but-slow fp32 fallback if workspace is too small for bf16 staging.
__global__ void naive_fallback(const float* __restrict__ x, const int* __restrict__ w_q,
                               const float* __restrict__ s_w, const void* __restrict__ perm_raw,
                               const float* __restrict__ bias, float* __restrict__ out) {
  int t = blockIdx.x * blockDim.x + threadIdx.x;
  int m = t >> 12;
  int o = t & 4095;
  const int f = g_perm_is64;
  const long long* p64 = (const long long*)perm_raw;
  const int*       p32 = (const int*)perm_raw;
  const float* xr = x + (size_t)m * IN_F;
  const int*   wr = w_q + (size_t)o * IN_F;
  float acc = 0.f;
  for (int g = 0; g < NG; ++g) {
    float part = 0.f;
    for (int k = 0; k < GRP; ++k) {
      int j = g * GRP + k;
      int pj = f ? (int)p64[j] : p32[j];
      part += xr[pj] * (float)wr[j];
    }
    acc += part * s_w[(size_t)g * OUT_F + o];
  }
  out[t] = acc + bias[o];
}

extern "C" void kernel_launch(void* const* d_in, const int* in_sizes, int n_in,
                              void* d_out, int out_size, void* d_ws, size_t ws_size,
                              hipStream_t stream) {
  const float* x    = (const float*)d_in[0];
  const int*   w_q  = (const int*)d_in[1];
  const float* s_w  = (const float*)d_in[2];
  const void*  perm = d_in[3];   // int64 or int32 -- detected on device
  const float* bias = (const float*)d_in[4];
  float* out = (float*)d_out;

  const size_t xp_bytes = (size_t)M_ROWS * IN_F * sizeof(__hip_bfloat16);  // 16 MiB
  const size_t wf_bytes = (size_t)OUT_F * IN_F * sizeof(__hip_bfloat16);   // 32 MiB

  if (ws_size < xp_bytes + wf_bytes) {
    decode_flag<<<1, 64, 0, stream>>>(perm);
    naive_fallback<<<(M_ROWS * OUT_F) / 256, 256, 0, stream>>>(x, w_q, s_w, perm, bias, out);
    return;
  }

  __hip_bfloat16* xp = (__hip_bfloat16*)d_ws;
  __hip_bfloat16* wf = (__hip_bfloat16*)((char*)d_ws + xp_bytes);

  prep<<<M_ROWS + (OUT_F * IN_F / 8) / 256, 256, 0, stream>>>(x, w_q, s_w, perm, xp, wf);

  gemm_bt<<<512, 256, 0, stream>>>(xp, wf, bias, out);
}